// Round 6
// baseline (3979.085 us; speedup 1.0000x reference)
//
#include <hip/hip_runtime.h>
#include <math.h>

#define BB   64      // batch
#define TT_  1024    // sequence length
#define UU   512     // hidden units
#define VV   256     // vocab (output)
#define EE   256     // embedding dim
#define TC   128     // time chunk (8 dispatches)

__device__ __forceinline__ float tanh_fast(float x) {
    // tanh(x) = 1 - 2/(e^{2x}+1); abs err ~1e-6 (validated: absmax 6e-5 end-to-end)
    float e = __expf(x + x);
    return 1.f - 2.f * __builtin_amdgcn_rcpf(e + 1.f);
}

// hstage float4-index swizzle (R4-measured: SQ_LDS_BANK_CONFLICT == 0)
__device__ __forceinline__ int swz(int a) {
    return a ^ (((a >> 3) & 7) ^ ((a >> 6) & 1));
}

// ---------------- E2 = emb @ Wx + b : [256, 512] ----------------
__global__ __launch_bounds__(512) void e2_kernel(
    const float* __restrict__ emb, const float* __restrict__ Wx,
    const float* __restrict__ bias, float* __restrict__ E2)
{
    const int v = blockIdx.x;
    const int u = threadIdx.x;
    float acc = bias[u];
    const float* er = emb + v * EE;
    #pragma unroll 8
    for (int e = 0; e < EE; ++e)
        acc = fmaf(er[e], Wx[e * UU + u], acc);
    E2[v * UU + u] = acc;
}

// ---------------- fused recurrence + logits (Wh in LDS, fused h reads) ------
// 256 blocks (1/CU), 512 thr = 8 waves. bg = bid&31 (2 batches), ug = bid>>5.
// Group-of-8 blocks (same bg) exchange h via hpub[(slot,b,u)] = (tag<<32|fp32),
// dual-published (volatile sc0 + agent atomic). Poll = baseline-proven: 24
// bounded sc0 rounds, then agent-scope spin with s_sleep (never hangs).
// REGISTER LESSON (R2/R4): the RA refuses >~104 VGPR for this kernel at HIP
// level; a 96-float weight file spills (3.5us/step, twice measured). So: Wh
// lives in LDS (128.5KB, swizzled: idx = ks*257 + r*16 + quad -> matvec read
// phases are 2-way max = free), only Wd (32 floats) is register-resident.
// Resource profile (139KB LDS / ~95 VGPR / 1 block/CU) == the baseline's
// proven-stable shape.
// FUSED h READS (new win): logits role (v0 = ug*32+2*quad, u-slice = matvec
// k-slice [16ks,+16)) -> the matvec's 8 hstage ds_read_b128 ALSO feed the
// logits FMAs inline (j = 4g+m). Logits' separate DS reads are gone; per-step
// DS = 128 (Wh) + 64 (h) b128-instr/CU.
// Matvec: lane (quad=2w+qsel, ks) accums 16k x 4u x 2b from WhLDS fragments;
// 5-level shfl_xor; lanes ks<4 finalize (static select, no rule-#20 scratch),
// publish; logits reduce (20 shfl) after publish overlaps peer exchange;
// ks==0 lanes store 4 outputs. No atomics, no out memset.
__global__ __launch_bounds__(512)
void rnn_chunk_kernel(
    const int* __restrict__ toks, const float* __restrict__ E2,
    const float* __restrict__ Wh, const float* __restrict__ Wd,
    const float* __restrict__ bd,
    unsigned long long* hpub,     // [2][BB][UU] (tag,val) pairs
    float* out, int t0, int last)
{
    __shared__ __align__(16) float4 WhL4[8224];        // 128.5 KB (swizzled)
    __shared__ __align__(16) float hstage[2][2][UU];   // 8 KB (swizzled)
    __shared__ __align__(16) float xps[2][2][64];      // 1 KB
    __shared__ int stok[2][TC];                        // 1 KB

    const int bid  = blockIdx.x;
    const int bg   = bid & 31;
    const int ug   = bid >> 5;
    const int tid  = threadIdx.x;
    const int w    = tid >> 6;
    const int lane = tid & 63;
    const int b0   = bg * 2;

    // unified roles: thread (quad, ks) does matvec units [ug*64+quad*4,+4) over
    // k [16ks,+16) AND logits v {ug*32+2quad, +1} over u [16ks,+16)
    const int qsel = lane >> 5;          // 0/1
    const int ks   = lane & 31;          // k/u slice [ks*16, +16)
    const int quad = w * 2 + qsel;       // [0,16)
    const int fmv  = ((ks >> 1) & 7) ^ ((ks >> 4) & 1);   // swz term, a = 4ks+g
    const int v0   = ug * 32 + quad * 2;

    // ---- Wd column pair -> registers (32 floats; fits the ~104 budget) ----
    float wdreg[32];                     // [j]=Wd[16ks+j][v0], [16+j]=..[v0+1]
    #pragma unroll
    for (int j = 0; j < 16; ++j) {
        const float2 wd2 = *(const float2*)(Wd + (ks * 16 + j) * VV + v0);
        wdreg[j]      = wd2.x;
        wdreg[16 + j] = wd2.y;
    }
    const float bdv0 = bd[v0];
    const float bdv1 = bd[v0 + 1];

    // ---- Wh slice -> LDS (once per dispatch), swizzled layout ----
    // writer thread (kw = tid>>4, qw = tid&15): rows kw*16+r, float4-col
    // ug*16+qw -> WhL4[kw*257 + r*16 + qw]. Reads (fixed r-group, 16-lane
    // phase: quad fixed, ks 0..15): idx%8 = (ks+quad)%8 -> 8 groups x2 = free.
    {
        const int kw = tid >> 4, qw = tid & 15;
        const float4* Wh4 = (const float4*)Wh;   // [512][128]
        #pragma unroll
        for (int r = 0; r < 16; ++r)
            WhL4[kw * 257 + r * 16 + qw] = Wh4[(kw * 16 + r) * 128 + ug * 16 + qw];
    }
    const float4* whb = WhL4 + ks * 257 + quad;

    // ---- chunk tokens + xp(t0) staging ----
    if (tid < 256) {
        const int b = tid >> 7, q = tid & 127;
        stok[b][q] = toks[(b0 + b) * TT_ + t0 + q];
    }
    if (tid < 128) {
        const int b = tid >> 6, u = tid & 63;
        xps[0][b][u] = E2[toks[(b0 + b) * TT_ + t0] * UU + ug * 64 + u];
    }
    __syncthreads();

    for (int tt = 0; tt < TC; ++tt) {
        const int s  = t0 + tt;
        const int sl = (s - 1) & 1;

        // ---- poll h(s-1) (skip own slice except at chunk start) ----
        if (s > 0 && (w != ug || tt == 0)) {
            unsigned long long* a0 = hpub + ((size_t)sl * BB + b0) * UU + w * 64 + lane;
            unsigned long long* a1 = a0 + UU;
            volatile const unsigned long long* f0 = a0;
            volatile const unsigned long long* f1 = a1;
            const unsigned int want = (unsigned int)(s - 1);
            unsigned long long p0 = 0, p1 = 0;
            bool got = false;
            for (int it = 0; it < 24; ++it) {     // sc0 fast rounds (local-XCD L2)
                p0 = *f0; p1 = *f1;
                unsigned long long ok =
                    __ballot((unsigned int)(p0 >> 32) == want) &
                    __ballot((unsigned int)(p1 >> 32) == want);
                if (ok == 0xFFFFFFFFFFFFFFFFull) { got = true; break; }
            }
            if (!got) {                           // proven agent-scope fallback
                while (true) {
                    p0 = __hip_atomic_load(a0, __ATOMIC_RELAXED, __HIP_MEMORY_SCOPE_AGENT);
                    p1 = __hip_atomic_load(a1, __ATOMIC_RELAXED, __HIP_MEMORY_SCOPE_AGENT);
                    unsigned long long ok =
                        __ballot((unsigned int)(p0 >> 32) == want) &
                        __ballot((unsigned int)(p1 >> 32) == want);
                    if (ok == 0xFFFFFFFFFFFFFFFFull) break;
                    __builtin_amdgcn_s_sleep(1);
                }
            }
            // stage swizzled: u = w*64+lane -> float4 a = w*16+(lane>>2), elem lane&3
            const int aa = w * 16 + (lane >> 2);
            const int fi = swz(aa) * 4 + (lane & 3);
            hstage[sl][0][fi] = __uint_as_float((unsigned int)p0);
            hstage[sl][1][fi] = __uint_as_float((unsigned int)p1);
        }
        __syncthreads();

        // ---- xp prefetch for s+1: issue load now, LDS-write after matvec ----
        float xpre = 0.f;
        const bool dopre = (tid < 128) && (tt + 1 < TC);
        if (dopre)
            xpre = E2[stok[tid >> 6][tt + 1] * UU + ug * 64 + (tid & 63)];

        // ---- fused matvec + logits FMAs: h fragments loaded ONCE ----
        float acc0[4] = {0.f, 0.f, 0.f, 0.f};
        float acc1[4] = {0.f, 0.f, 0.f, 0.f};
        float s00 = 0.f, s01 = 0.f, s10 = 0.f, s11 = 0.f;
        if (s > 0) {
            const float* H0 = hstage[sl][0];
            const float* H1 = hstage[sl][1];
            #pragma unroll
            for (int g = 0; g < 4; ++g) {
                const int as2 = (4 * ks + g) ^ fmv;
                const float4 ha = *(const float4*)(H0 + as2 * 4);
                const float4 hc = *(const float4*)(H1 + as2 * 4);
                const float av[4] = {ha.x, ha.y, ha.z, ha.w};
                const float cv[4] = {hc.x, hc.y, hc.z, hc.w};
                #pragma unroll
                for (int m = 0; m < 4; ++m) {
                    const float4 wv = whb[(g * 4 + m) * 16];
                    acc0[0] = fmaf(av[m], wv.x, acc0[0]);
                    acc0[1] = fmaf(av[m], wv.y, acc0[1]);
                    acc0[2] = fmaf(av[m], wv.z, acc0[2]);
                    acc0[3] = fmaf(av[m], wv.w, acc0[3]);
                    acc1[0] = fmaf(cv[m], wv.x, acc1[0]);
                    acc1[1] = fmaf(cv[m], wv.y, acc1[1]);
                    acc1[2] = fmaf(cv[m], wv.z, acc1[2]);
                    acc1[3] = fmaf(cv[m], wv.w, acc1[3]);
                    // logits(s-1): same h fragment, Wd from registers
                    s00 = fmaf(av[m], wdreg[4 * g + m],      s00);
                    s01 = fmaf(av[m], wdreg[16 + 4 * g + m], s01);
                    s10 = fmaf(cv[m], wdreg[4 * g + m],      s10);
                    s11 = fmaf(cv[m], wdreg[16 + 4 * g + m], s11);
                }
            }
            // reduce matvec accs over ks (5 levels); all lanes get full sums
            #pragma unroll
            for (int off = 1; off < 32; off <<= 1) {
                #pragma unroll
                for (int c = 0; c < 4; ++c) {
                    acc0[c] += __shfl_xor(acc0[c], off, 64);
                    acc1[c] += __shfl_xor(acc1[c], off, 64);
                }
            }
        }
        // deferred xp LDS write (load latency hidden under matvec)
        if (dopre)
            xps[(s + 1) & 1][tid >> 6][tid & 63] = xpre;

        // ---- finalize + publish h(s): lanes ks<4, one unit each ----
        if (ks < 4) {
            // static-select the lane's accumulator (runtime acc[ks] = scratch!)
            const float r0 = (ks == 0) ? acc0[0] : (ks == 1) ? acc0[1]
                           : (ks == 2) ? acc0[2] : acc0[3];
            const float r1 = (ks == 0) ? acc1[0] : (ks == 1) ? acc1[1]
                           : (ks == 2) ? acc1[2] : acc1[3];
            const float h0 = tanh_fast(r0 + xps[s & 1][0][quad * 4 + ks]);
            const float h1 = tanh_fast(r1 + xps[s & 1][1][quad * 4 + ks]);
            unsigned long long* dst0 =
                hpub + ((size_t)(s & 1) * BB + b0) * UU + ug * 64 + quad * 4 + ks;
            unsigned long long* dst1 = dst0 + UU;
            const unsigned long long tg = (unsigned long long)(unsigned int)s << 32;
            const unsigned long long pk0 = tg | __float_as_uint(h0);
            const unsigned long long pk1 = tg | __float_as_uint(h1);
            *(volatile unsigned long long*)dst0 = pk0;   // sc0 local-L2 copy
            *(volatile unsigned long long*)dst1 = pk1;
            __hip_atomic_store(dst0, pk0, __ATOMIC_RELAXED, __HIP_MEMORY_SCOPE_AGENT);
            __hip_atomic_store(dst1, pk1, __ATOMIC_RELAXED, __HIP_MEMORY_SCOPE_AGENT);
            const int asf = swz(ug * 16 + quad);
            hstage[s & 1][0][asf * 4 + ks] = h0;
            hstage[s & 1][1][asf * 4 + ks] = h1;
        }

        // ---- logits(s-1) reduce + store (overlaps peer publish window) ----
        if (s > 0) {
            #pragma unroll
            for (int off = 1; off < 32; off <<= 1) {
                s00 += __shfl_xor(s00, off, 64);
                s01 += __shfl_xor(s01, off, 64);
                s10 += __shfl_xor(s10, off, 64);
                s11 += __shfl_xor(s11, off, 64);
            }
            if (ks == 0) {
                float* o0 = out + ((size_t)b0 * TT_ + (s - 1)) * VV + v0;
                float* o1 = o0 + (size_t)TT_ * VV;
                o0[0] = s00 + bdv0;
                o0[1] = s01 + bdv1;
                o1[0] = s10 + bdv0;
                o1[1] = s11 + bdv1;
            }
        }
    }

    // ---- last chunk epilogue: logits(1023) needs full h(1023) staged ----
    if (last) {
        const int s  = t0 + TC - 1;          // 1023
        const int sl = s & 1;
        if (w != ug) {   // own slice already in hstage from tt=TC-1 finalize
            unsigned long long* a0 = hpub + ((size_t)sl * BB + b0) * UU + w * 64 + lane;
            unsigned long long* a1 = a0 + UU;
            volatile const unsigned long long* f0 = a0;
            volatile const unsigned long long* f1 = a1;
            const unsigned int want = (unsigned int)s;
            unsigned long long p0 = 0, p1 = 0;
            bool got = false;
            for (int it = 0; it < 24; ++it) {
                p0 = *f0; p1 = *f1;
                unsigned long long ok =
                    __ballot((unsigned int)(p0 >> 32) == want) &
                    __ballot((unsigned int)(p1 >> 32) == want);
                if (ok == 0xFFFFFFFFFFFFFFFFull) { got = true; break; }
            }
            if (!got) {
                while (true) {
                    p0 = __hip_atomic_load(a0, __ATOMIC_RELAXED, __HIP_MEMORY_SCOPE_AGENT);
                    p1 = __hip_atomic_load(a1, __ATOMIC_RELAXED, __HIP_MEMORY_SCOPE_AGENT);
                    unsigned long long ok =
                        __ballot((unsigned int)(p0 >> 32) == want) &
                        __ballot((unsigned int)(p1 >> 32) == want);
                    if (ok == 0xFFFFFFFFFFFFFFFFull) break;
                    __builtin_amdgcn_s_sleep(1);
                }
            }
            const int aa = w * 16 + (lane >> 2);
            const int fi = swz(aa) * 4 + (lane & 3);
            hstage[sl][0][fi] = __uint_as_float((unsigned int)p0);
            hstage[sl][1][fi] = __uint_as_float((unsigned int)p1);
        }
        __syncthreads();
        {
            const float* H0 = hstage[sl][0];
            const float* H1 = hstage[sl][1];
            float s00 = 0.f, s01 = 0.f, s10 = 0.f, s11 = 0.f;
            #pragma unroll
            for (int g = 0; g < 4; ++g) {
                const int as2 = (4 * ks + g) ^ fmv;
                const float4 ha = *(const float4*)(H0 + as2 * 4);
                const float4 hc = *(const float4*)(H1 + as2 * 4);
                const float av[4] = {ha.x, ha.y, ha.z, ha.w};
                const float cv[4] = {hc.x, hc.y, hc.z, hc.w};
                #pragma unroll
                for (int m = 0; m < 4; ++m) {
                    s00 = fmaf(av[m], wdreg[4 * g + m],      s00);
                    s01 = fmaf(av[m], wdreg[16 + 4 * g + m], s01);
                    s10 = fmaf(cv[m], wdreg[4 * g + m],      s10);
                    s11 = fmaf(cv[m], wdreg[16 + 4 * g + m], s11);
                }
            }
            #pragma unroll
            for (int off = 1; off < 32; off <<= 1) {
                s00 += __shfl_xor(s00, off, 64);
                s01 += __shfl_xor(s01, off, 64);
                s10 += __shfl_xor(s10, off, 64);
                s11 += __shfl_xor(s11, off, 64);
            }
            if (ks == 0) {
                float* o0 = out + ((size_t)b0 * TT_ + s) * VV + v0;
                float* o1 = o0 + (size_t)TT_ * VV;
                o0[0] = s00 + bdv0;
                o0[1] = s01 + bdv1;
                o1[0] = s10 + bdv0;
                o1[1] = s11 + bdv1;
            }
        }
    }
}

extern "C" void kernel_launch(void* const* d_in, const int* in_sizes, int n_in,
                              void* d_out, int out_size, void* d_ws, size_t ws_size,
                              hipStream_t stream)
{
    (void)in_sizes; (void)n_in; (void)ws_size; (void)out_size;

    const int*   toks = (const int*)  d_in[0];
    const float* emb  = (const float*)d_in[1];
    const float* Wx   = (const float*)d_in[2];
    const float* Wh   = (const float*)d_in[3];
    const float* bias = (const float*)d_in[4];
    const float* Wd   = (const float*)d_in[5];
    const float* bd   = (const float*)d_in[6];
    float* out = (float*)d_out;

    // ws layout: hpub [2*BB*UU] u64 (512 KB) | E2 [EE*UU] f32 (512 KB)
    unsigned long long* hpub = (unsigned long long*)d_ws;
    float* E2 = (float*)(hpub + 2 * BB * UU);

    // invalidate tags (0xFFFFFFFF matches no step) -> no stale-tag match on first run
    hipMemsetAsync(hpub, 0xFF, (size_t)(2 * BB * UU) * sizeof(unsigned long long), stream);
    e2_kernel<<<EE, UU, 0, stream>>>(emb, Wx, bias, E2);

    for (int c = 0; c < TT_ / TC; ++c) {
        const int t0 = c * TC;
        rnn_chunk_kernel<<<256, 512, 0, stream>>>(
            toks, E2, Wh, Wd, bd, hpub, out, t0, c == (TT_ / TC - 1));
    }
}

// Round 7
// 3269.874 us; speedup vs baseline: 1.2169x; 1.2169x over previous
//
#include <hip/hip_runtime.h>
#include <math.h>

#define BB   64      // batch
#define TT_  1024    // sequence length
#define UU   512     // hidden units
#define VV   256     // vocab (output)
#define EE   256     // embedding dim
#define TC   128     // time chunk (8 dispatches)

__device__ __forceinline__ float tanh_fast(float x) {
    // tanh(x) = 1 - 2/(e^{2x}+1); abs err ~1e-6 (validated: absmax 6e-5 end-to-end)
    float e = __expf(x + x);
    return 1.f - 2.f * __builtin_amdgcn_rcpf(e + 1.f);
}

// hstage float4-index swizzle (R4/R6-measured: SQ_LDS_BANK_CONFLICT == 0)
__device__ __forceinline__ int swz(int a) {
    return a ^ (((a >> 3) & 7) ^ ((a >> 6) & 1));
}

// ---------------- E2 = emb @ Wx + b : [256, 512] ----------------
__global__ __launch_bounds__(512) void e2_kernel(
    const float* __restrict__ emb, const float* __restrict__ Wx,
    const float* __restrict__ bias, float* __restrict__ E2)
{
    const int v = blockIdx.x;
    const int u = threadIdx.x;
    float acc = bias[u];
    const float* er = emb + v * EE;
    #pragma unroll 8
    for (int e = 0; e < EE; ++e)
        acc = fmaf(er[e], Wx[e * UU + u], acc);
    E2[v * UU + u] = acc;
}

// ---------------- fused recurrence + logits -------------------------------
// 256 blocks (1/CU), 512 thr = 8 waves. bg = bid&31 (2 batches), ug = bid>>5.
// Group-of-8 blocks (same bg) exchange h via hpub[(slot,b,u)] = (tag<<32|fp32),
// dual-published (volatile sc0 + agent atomic). Poll = baseline-proven: 24
// bounded sc0 rounds, then agent-scope spin with s_sleep (never hangs).
// R6 POST-MORTEM (measured 9500cy/step, VALUBusy 19%, conflicts 0): the DS
// pipe was the bottleneck -- 24 b128 (Wh+h) + 60 shfl (ds_swizzle = DS pipe!)
// ~= 5300cy/step -- plus __syncthreads' implicit vmcnt(0) draining the
// agent-scope publish stores (~500+cy to device coherence point) every step.
// R7 FIXES (structure otherwise identical to R6):
//  1) FOLD-BUTTERFLY reductions: matvec 40->9 shfls (fold batch@xor16,
//     unit-pair@xor8, unit@xor4, then +1,+2), logits 20->6. Final value in
//     lane ks: matvec (b=(ks>>4)&1, c=2*bit3+bit2), logits (b=bit4, voff=bit3).
//  2) RAW BARRIER: s_waitcnt lgkmcnt(0) + s_barrier (8-phase-template
//     pattern) -- LDS ordering kept, publish/out stores + prefetch loads stay
//     in flight across the barrier (no per-step vmcnt drain).
// Wh in LDS (128.5KB swizzled, conflict-free, measured), Wd (32f) in regs,
// fused h reads feed matvec AND logits FMAs. No atomics, no out memset.
__global__ __launch_bounds__(512)
void rnn_chunk_kernel(
    const int* __restrict__ toks, const float* __restrict__ E2,
    const float* __restrict__ Wh, const float* __restrict__ Wd,
    const float* __restrict__ bd,
    unsigned long long* hpub,     // [2][BB][UU] (tag,val) pairs
    float* out, int t0, int last)
{
    __shared__ __align__(16) float4 WhL4[8224];        // 128.5 KB (swizzled)
    __shared__ __align__(16) float hstage[2][2][UU];   // 8 KB (swizzled)
    __shared__ __align__(16) float xps[2][2][64];      // 1 KB
    __shared__ int stok[2][TC];                        // 1 KB

    const int bid  = blockIdx.x;
    const int bg   = bid & 31;
    const int ug   = bid >> 5;
    const int tid  = threadIdx.x;
    const int w    = tid >> 6;
    const int lane = tid & 63;
    const int b0   = bg * 2;

    // unified roles: thread (quad, ks) does matvec units [ug*64+quad*4,+4) over
    // k [16ks,+16) AND logits v {ug*32+2quad, +1} over u [16ks,+16)
    const int qsel = lane >> 5;          // 0/1
    const int ks   = lane & 31;          // k/u slice [ks*16, +16)
    const int quad = w * 2 + qsel;       // [0,16)
    const int fmv  = ((ks >> 1) & 7) ^ ((ks >> 4) & 1);   // swz term, a = 4ks+g
    const int v0   = ug * 32 + quad * 2;

    // ---- Wd column pair -> registers (32 floats) ----
    float wdreg[32];                     // [j]=Wd[16ks+j][v0], [16+j]=..[v0+1]
    #pragma unroll
    for (int j = 0; j < 16; ++j) {
        const float2 wd2 = *(const float2*)(Wd + (ks * 16 + j) * VV + v0);
        wdreg[j]      = wd2.x;
        wdreg[16 + j] = wd2.y;
    }
    const float bdv0 = bd[v0];
    const float bdv1 = bd[v0 + 1];

    // ---- Wh slice -> LDS (once per dispatch), swizzled layout ----
    {
        const int kw = tid >> 4, qw = tid & 15;
        const float4* Wh4 = (const float4*)Wh;   // [512][128]
        #pragma unroll
        for (int r = 0; r < 16; ++r)
            WhL4[kw * 257 + r * 16 + qw] = Wh4[(kw * 16 + r) * 128 + ug * 16 + qw];
    }
    const float4* whb = WhL4 + ks * 257 + quad;

    // ---- chunk tokens + xp(t0) staging ----
    if (tid < 256) {
        const int b = tid >> 7, q = tid & 127;
        stok[b][q] = toks[(b0 + b) * TT_ + t0 + q];
    }
    if (tid < 128) {
        const int b = tid >> 6, u = tid & 63;
        xps[0][b][u] = E2[toks[(b0 + b) * TT_ + t0] * UU + ug * 64 + u];
    }
    __syncthreads();

    for (int tt = 0; tt < TC; ++tt) {
        const int s  = t0 + tt;
        const int sl = (s - 1) & 1;

        // ---- poll h(s-1) (skip own slice except at chunk start) ----
        if (s > 0 && (w != ug || tt == 0)) {
            unsigned long long* a0 = hpub + ((size_t)sl * BB + b0) * UU + w * 64 + lane;
            unsigned long long* a1 = a0 + UU;
            volatile const unsigned long long* f0 = a0;
            volatile const unsigned long long* f1 = a1;
            const unsigned int want = (unsigned int)(s - 1);
            unsigned long long p0 = 0, p1 = 0;
            bool got = false;
            for (int it = 0; it < 24; ++it) {     // sc0 fast rounds (local-XCD L2)
                p0 = *f0; p1 = *f1;
                unsigned long long ok =
                    __ballot((unsigned int)(p0 >> 32) == want) &
                    __ballot((unsigned int)(p1 >> 32) == want);
                if (ok == 0xFFFFFFFFFFFFFFFFull) { got = true; break; }
            }
            if (!got) {                           // proven agent-scope fallback
                while (true) {
                    p0 = __hip_atomic_load(a0, __ATOMIC_RELAXED, __HIP_MEMORY_SCOPE_AGENT);
                    p1 = __hip_atomic_load(a1, __ATOMIC_RELAXED, __HIP_MEMORY_SCOPE_AGENT);
                    unsigned long long ok =
                        __ballot((unsigned int)(p0 >> 32) == want) &
                        __ballot((unsigned int)(p1 >> 32) == want);
                    if (ok == 0xFFFFFFFFFFFFFFFFull) break;
                    __builtin_amdgcn_s_sleep(1);
                }
            }
            // stage swizzled: u = w*64+lane -> float4 a = w*16+(lane>>2), elem lane&3
            const int aa = w * 16 + (lane >> 2);
            const int fi = swz(aa) * 4 + (lane & 3);
            hstage[sl][0][fi] = __uint_as_float((unsigned int)p0);
            hstage[sl][1][fi] = __uint_as_float((unsigned int)p1);
        }
        // RAW barrier: order LDS (lgkmcnt) but let publish/out stores and
        // prefetch loads stay in flight (no vmcnt(0) drain -- the R6 stall).
        asm volatile("s_waitcnt lgkmcnt(0)" ::: "memory");
        __builtin_amdgcn_s_barrier();

        // ---- xp prefetch for s+1: issue load now, LDS-write after matvec ----
        float xpre = 0.f;
        const bool dopre = (tid < 128) && (tt + 1 < TC);
        if (dopre)
            xpre = E2[stok[tid >> 6][tt + 1] * UU + ug * 64 + (tid & 63)];

        // ---- fused matvec + logits FMAs: h fragments loaded ONCE ----
        float acc0[4] = {0.f, 0.f, 0.f, 0.f};
        float acc1[4] = {0.f, 0.f, 0.f, 0.f};
        float s00 = 0.f, s01 = 0.f, s10 = 0.f, s11 = 0.f;
        if (s > 0) {
            const float* H0 = hstage[sl][0];
            const float* H1 = hstage[sl][1];
            #pragma unroll
            for (int g = 0; g < 4; ++g) {
                const int as2 = (4 * ks + g) ^ fmv;
                const float4 ha = *(const float4*)(H0 + as2 * 4);
                const float4 hc = *(const float4*)(H1 + as2 * 4);
                const float av[4] = {ha.x, ha.y, ha.z, ha.w};
                const float cv[4] = {hc.x, hc.y, hc.z, hc.w};
                #pragma unroll
                for (int m = 0; m < 4; ++m) {
                    const float4 wv = whb[(g * 4 + m) * 16];
                    acc0[0] = fmaf(av[m], wv.x, acc0[0]);
                    acc0[1] = fmaf(av[m], wv.y, acc0[1]);
                    acc0[2] = fmaf(av[m], wv.z, acc0[2]);
                    acc0[3] = fmaf(av[m], wv.w, acc0[3]);
                    acc1[0] = fmaf(cv[m], wv.x, acc1[0]);
                    acc1[1] = fmaf(cv[m], wv.y, acc1[1]);
                    acc1[2] = fmaf(cv[m], wv.z, acc1[2]);
                    acc1[3] = fmaf(cv[m], wv.w, acc1[3]);
                    // logits(s-1): same h fragment, Wd from registers
                    s00 = fmaf(av[m], wdreg[4 * g + m],      s00);
                    s01 = fmaf(av[m], wdreg[16 + 4 * g + m], s01);
                    s10 = fmaf(cv[m], wdreg[4 * g + m],      s10);
                    s11 = fmaf(cv[m], wdreg[16 + 4 * g + m], s11);
                }
            }
        }
        // deferred xp LDS write (load latency hidden under matvec)
        if (dopre)
            xps[(s + 1) & 1][tid >> 6][tid & 63] = xpre;

        // ---- matvec fold-reduce: 8 vals over 32 ks-lanes in 9 shfls ----
        // xor16 folds batch (keep acc0 if ks<16 else acc1), xor8 folds unit-
        // pair, xor4 folds unit-lo, +1/+2 finish. Result v in EVERY lane:
        // value (b=(ks>>4)&1, c=2*((ks>>3)&1)+((ks>>2)&1)), 4-fold replicated.
        float tba[4];
        #pragma unroll
        for (int c = 0; c < 4; ++c) {
            const float x = (ks & 16) ? acc0[c] : acc1[c];
            const float y = __shfl_xor(x, 16, 64);
            tba[c] = ((ks & 16) ? acc1[c] : acc0[c]) + y;
        }
        float ua, ub;
        {
            const float x0 = (ks & 8) ? tba[0] : tba[2];
            const float x1 = (ks & 8) ? tba[1] : tba[3];
            const float y0 = __shfl_xor(x0, 8, 64);
            const float y1 = __shfl_xor(x1, 8, 64);
            ua = ((ks & 8) ? tba[2] : tba[0]) + y0;
            ub = ((ks & 8) ? tba[3] : tba[1]) + y1;
        }
        float v;
        {
            const float x = (ks & 4) ? ua : ub;
            const float y = __shfl_xor(x, 4, 64);
            v = ((ks & 4) ? ub : ua) + y;
        }
        v += __shfl_xor(v, 1, 64);
        v += __shfl_xor(v, 2, 64);

        // ---- logits fold-reduce: 4 vals over 32 lanes in 6 shfls ----
        // Result L: value (b=(ks>>4)&1, voff=(ks>>3)&1), 8-fold replicated.
        float pa, pb;
        {
            const float x0 = (ks & 16) ? s00 : s10;
            const float x1 = (ks & 16) ? s01 : s11;
            const float y0 = __shfl_xor(x0, 16, 64);
            const float y1 = __shfl_xor(x1, 16, 64);
            pa = ((ks & 16) ? s10 : s00) + y0;
            pb = ((ks & 16) ? s11 : s01) + y1;
        }
        float L;
        {
            const float x = (ks & 8) ? pa : pb;
            const float y = __shfl_xor(x, 8, 64);
            L = ((ks & 8) ? pb : pa) + y;
        }
        L += __shfl_xor(L, 1, 64);
        L += __shfl_xor(L, 2, 64);
        L += __shfl_xor(L, 4, 64);

        // ---- finalize + publish h(s): lanes (ks&3)==0, one (b,u) each ----
        if ((ks & 3) == 0) {
            const int b = (ks >> 4) & 1;
            const int c = (((ks >> 3) & 1) << 1) | ((ks >> 2) & 1);
            const int u = quad * 4 + c;
            const float h = tanh_fast(v + xps[s & 1][b][u]);
            unsigned long long* dst =
                hpub + ((size_t)(s & 1) * BB + b0 + b) * UU + ug * 64 + u;
            const unsigned long long pk =
                ((unsigned long long)(unsigned int)s << 32) | __float_as_uint(h);
            *(volatile unsigned long long*)dst = pk;   // sc0 local-L2 copy
            __hip_atomic_store(dst, pk, __ATOMIC_RELAXED, __HIP_MEMORY_SCOPE_AGENT);
            hstage[s & 1][b][swz(ug * 16 + quad) * 4 + c] = h;
        }

        // ---- logits(s-1) store: lanes (ks&7)==0, one (b, v0+voff) each ----
        if (s > 0 && (ks & 7) == 0) {
            const int b    = (ks >> 4) & 1;
            const int voff = (ks >> 3) & 1;
            out[((size_t)(b0 + b) * TT_ + (s - 1)) * VV + v0 + voff]
                = L + (voff ? bdv1 : bdv0);
        }
    }

    // ---- last chunk epilogue: logits(1023) needs full h(1023) staged ----
    if (last) {
        const int s  = t0 + TC - 1;          // 1023
        const int sl = s & 1;
        if (w != ug) {   // own slice already in hstage from tt=TC-1 finalize
            unsigned long long* a0 = hpub + ((size_t)sl * BB + b0) * UU + w * 64 + lane;
            unsigned long long* a1 = a0 + UU;
            volatile const unsigned long long* f0 = a0;
            volatile const unsigned long long* f1 = a1;
            const unsigned int want = (unsigned int)s;
            unsigned long long p0 = 0, p1 = 0;
            bool got = false;
            for (int it = 0; it < 24; ++it) {
                p0 = *f0; p1 = *f1;
                unsigned long long ok =
                    __ballot((unsigned int)(p0 >> 32) == want) &
                    __ballot((unsigned int)(p1 >> 32) == want);
                if (ok == 0xFFFFFFFFFFFFFFFFull) { got = true; break; }
            }
            if (!got) {
                while (true) {
                    p0 = __hip_atomic_load(a0, __ATOMIC_RELAXED, __HIP_MEMORY_SCOPE_AGENT);
                    p1 = __hip_atomic_load(a1, __ATOMIC_RELAXED, __HIP_MEMORY_SCOPE_AGENT);
                    unsigned long long ok =
                        __ballot((unsigned int)(p0 >> 32) == want) &
                        __ballot((unsigned int)(p1 >> 32) == want);
                    if (ok == 0xFFFFFFFFFFFFFFFFull) break;
                    __builtin_amdgcn_s_sleep(1);
                }
            }
            const int aa = w * 16 + (lane >> 2);
            const int fi = swz(aa) * 4 + (lane & 3);
            hstage[sl][0][fi] = __uint_as_float((unsigned int)p0);
            hstage[sl][1][fi] = __uint_as_float((unsigned int)p1);
        }
        __syncthreads();
        {
            const float* H0 = hstage[sl][0];
            const float* H1 = hstage[sl][1];
            float s00 = 0.f, s01 = 0.f, s10 = 0.f, s11 = 0.f;
            #pragma unroll
            for (int g = 0; g < 4; ++g) {
                const int as2 = (4 * ks + g) ^ fmv;
                const float4 ha = *(const float4*)(H0 + as2 * 4);
                const float4 hc = *(const float4*)(H1 + as2 * 4);
                const float av[4] = {ha.x, ha.y, ha.z, ha.w};
                const float cv[4] = {hc.x, hc.y, hc.z, hc.w};
                #pragma unroll
                for (int m = 0; m < 4; ++m) {
                    s00 = fmaf(av[m], wdreg[4 * g + m],      s00);
                    s01 = fmaf(av[m], wdreg[16 + 4 * g + m], s01);
                    s10 = fmaf(cv[m], wdreg[4 * g + m],      s10);
                    s11 = fmaf(cv[m], wdreg[16 + 4 * g + m], s11);
                }
            }
            float pa, pb;
            {
                const float x0 = (ks & 16) ? s00 : s10;
                const float x1 = (ks & 16) ? s01 : s11;
                const float y0 = __shfl_xor(x0, 16, 64);
                const float y1 = __shfl_xor(x1, 16, 64);
                pa = ((ks & 16) ? s10 : s00) + y0;
                pb = ((ks & 16) ? s11 : s01) + y1;
            }
            float L;
            {
                const float x = (ks & 8) ? pa : pb;
                const float y = __shfl_xor(x, 8, 64);
                L = ((ks & 8) ? pb : pa) + y;
            }
            L += __shfl_xor(L, 1, 64);
            L += __shfl_xor(L, 2, 64);
            L += __shfl_xor(L, 4, 64);
            if ((ks & 7) == 0) {
                const int b    = (ks >> 4) & 1;
                const int voff = (ks >> 3) & 1;
                out[((size_t)(b0 + b) * TT_ + s) * VV + v0 + voff]
                    = L + (voff ? bdv1 : bdv0);
            }
        }
    }
}

extern "C" void kernel_launch(void* const* d_in, const int* in_sizes, int n_in,
                              void* d_out, int out_size, void* d_ws, size_t ws_size,
                              hipStream_t stream)
{
    (void)in_sizes; (void)n_in; (void)ws_size; (void)out_size;

    const int*   toks = (const int*)  d_in[0];
    const float* emb  = (const float*)d_in[1];
    const float* Wx   = (const float*)d_in[2];
    const float* Wh   = (const float*)d_in[3];
    const float* bias = (const float*)d_in[4];
    const float* Wd   = (const float*)d_in[5];
    const float* bd   = (const float*)d_in[6];
    float* out = (float*)d_out;

    // ws layout: hpub [2*BB*UU] u64 (512 KB) | E2 [EE*UU] f32 (512 KB)
    unsigned long long* hpub = (unsigned long long*)d_ws;
    float* E2 = (float*)(hpub + 2 * BB * UU);

    // invalidate tags (0xFFFFFFFF matches no step) -> no stale-tag match on first run
    hipMemsetAsync(hpub, 0xFF, (size_t)(2 * BB * UU) * sizeof(unsigned long long), stream);
    e2_kernel<<<EE, UU, 0, stream>>>(emb, Wx, bias, E2);

    for (int c = 0; c < TT_ / TC; ++c) {
        const int t0 = c * TC;
        rnn_chunk_kernel<<<256, 512, 0, stream>>>(
            toks, E2, Wh, Wd, bd, hpub, out, t0, c == (TT_ / TC - 1));
    }
}

// Round 8
// 2503.472 us; speedup vs baseline: 1.5894x; 1.3061x over previous
//
#include <hip/hip_runtime.h>
#include <math.h>

#define BB   64      // batch
#define TT_  1024    // sequence length
#define UU   512     // hidden units
#define VV   256     // vocab (output)
#define EE   256     // embedding dim
#define TC   128     // time chunk (8 dispatches)

__device__ __forceinline__ float tanh_fast(float x) {
    // tanh(x) = 1 - 2/(e^{2x}+1); abs err ~1e-6 (validated: absmax 6e-5 end-to-end)
    float e = __expf(x + x);
    return 1.f - 2.f * __builtin_amdgcn_rcpf(e + 1.f);
}

// hstage float4-index swizzle (R4/R6-measured: SQ_LDS_BANK_CONFLICT == 0)
__device__ __forceinline__ int swz(int a) {
    return a ^ (((a >> 3) & 7) ^ ((a >> 6) & 1));
}

// ---------------- E2 = emb @ Wx + b : [256, 512] ----------------
__global__ __launch_bounds__(512) void e2_kernel(
    const float* __restrict__ emb, const float* __restrict__ Wx,
    const float* __restrict__ bias, float* __restrict__ E2)
{
    const int v = blockIdx.x;
    const int u = threadIdx.x;
    float acc = bias[u];
    const float* er = emb + v * EE;
    #pragma unroll 8
    for (int e = 0; e < EE; ++e)
        acc = fmaf(er[e], Wx[e * UU + u], acc);
    E2[v * UU + u] = acc;
}

// ---------------- fused recurrence + logits -------------------------------
// 256 blocks (1/CU), 512 thr = 8 waves. bg = bid&31 (2 batches), ug = bid>>5.
// Group-of-8 blocks (same bg) exchange h via hpub[(slot,b,u)] = (tag<<32|fp32),
// dual-published (volatile sc0 + agent atomic). Poll = baseline-proven: 24
// bounded sc0 rounds, then agent-scope spin with s_sleep (never hangs).
// R7 POST-MORTEM (7800cy/step measured; DS issue only ~3000cy): ~4500cy was
// serialized exchange latency. R7's fused logits put 64 FMA + 6 shfl BEFORE
// the publish on the serial chain, and left the post-publish exchange window
// idle. The baseline overlapped logits with the exchange -- that's why it won.
// R8 SCHEDULE (baseline's overlap + R7's mechanics):
//   poll h(s-1) -> stage -> lgkm barrier -> matvec (128 FMA, 24 b128) ->
//   fold-reduce (9 shfl) -> tanh -> PUBLISH h(s) -> logits(s-1) from staged
//   hstage[sl] (8 b128 + 64 FMA + 6 shfl + plain store, hidden in the
//   exchange window) -> next step.
// Race note: logits reads hstage[sl] ((s-1)&1); step s+2's stage writes to the
// same parity are separated by step s+1's lgkm barrier. Publish writes go to
// hstage[s&1] (other parity).
// Wh in LDS (128.5KB swizzled, conflict-free, measured), Wd (32f) in regs.
// No atomics, no out memset.
__global__ __launch_bounds__(512)
void rnn_chunk_kernel(
    const int* __restrict__ toks, const float* __restrict__ E2,
    const float* __restrict__ Wh, const float* __restrict__ Wd,
    const float* __restrict__ bd,
    unsigned long long* hpub,     // [2][BB][UU] (tag,val) pairs
    float* out, int t0, int last)
{
    __shared__ __align__(16) float4 WhL4[8224];        // 128.5 KB (swizzled)
    __shared__ __align__(16) float hstage[2][2][UU];   // 8 KB (swizzled)
    __shared__ __align__(16) float xps[2][2][64];      // 1 KB
    __shared__ int stok[2][TC];                        // 1 KB

    const int bid  = blockIdx.x;
    const int bg   = bid & 31;
    const int ug   = bid >> 5;
    const int tid  = threadIdx.x;
    const int w    = tid >> 6;
    const int lane = tid & 63;
    const int b0   = bg * 2;

    // roles: thread (quad, ks) does matvec units [ug*64+quad*4,+4) over
    // k [16ks,+16) AND logits v {ug*32+2quad, +1} over u [16ks,+16)
    const int qsel = lane >> 5;          // 0/1
    const int ks   = lane & 31;          // k/u slice [ks*16, +16)
    const int quad = w * 2 + qsel;       // [0,16)
    const int fmv  = ((ks >> 1) & 7) ^ ((ks >> 4) & 1);   // swz term, a = 4ks+g
    const int v0   = ug * 32 + quad * 2;

    // ---- Wd column pair -> registers (32 floats) ----
    float wdreg[32];                     // [j]=Wd[16ks+j][v0], [16+j]=..[v0+1]
    #pragma unroll
    for (int j = 0; j < 16; ++j) {
        const float2 wd2 = *(const float2*)(Wd + (ks * 16 + j) * VV + v0);
        wdreg[j]      = wd2.x;
        wdreg[16 + j] = wd2.y;
    }
    const float bdv0 = bd[v0];
    const float bdv1 = bd[v0 + 1];

    // ---- Wh slice -> LDS (once per dispatch), swizzled layout ----
    {
        const int kw = tid >> 4, qw = tid & 15;
        const float4* Wh4 = (const float4*)Wh;   // [512][128]
        #pragma unroll
        for (int r = 0; r < 16; ++r)
            WhL4[kw * 257 + r * 16 + qw] = Wh4[(kw * 16 + r) * 128 + ug * 16 + qw];
    }
    const float4* whb = WhL4 + ks * 257 + quad;

    // ---- chunk tokens + xp(t0) staging ----
    if (tid < 256) {
        const int b = tid >> 7, q = tid & 127;
        stok[b][q] = toks[(b0 + b) * TT_ + t0 + q];
    }
    if (tid < 128) {
        const int b = tid >> 6, u = tid & 63;
        xps[0][b][u] = E2[toks[(b0 + b) * TT_ + t0] * UU + ug * 64 + u];
    }
    __syncthreads();

    for (int tt = 0; tt < TC; ++tt) {
        const int s  = t0 + tt;
        const int sl = (s - 1) & 1;

        // ---- poll h(s-1) (skip own slice except at chunk start) ----
        if (s > 0 && (w != ug || tt == 0)) {
            unsigned long long* a0 = hpub + ((size_t)sl * BB + b0) * UU + w * 64 + lane;
            unsigned long long* a1 = a0 + UU;
            volatile const unsigned long long* f0 = a0;
            volatile const unsigned long long* f1 = a1;
            const unsigned int want = (unsigned int)(s - 1);
            unsigned long long p0 = 0, p1 = 0;
            bool got = false;
            for (int it = 0; it < 24; ++it) {     // sc0 fast rounds (local-XCD L2)
                p0 = *f0; p1 = *f1;
                unsigned long long ok =
                    __ballot((unsigned int)(p0 >> 32) == want) &
                    __ballot((unsigned int)(p1 >> 32) == want);
                if (ok == 0xFFFFFFFFFFFFFFFFull) { got = true; break; }
            }
            if (!got) {                           // proven agent-scope fallback
                while (true) {
                    p0 = __hip_atomic_load(a0, __ATOMIC_RELAXED, __HIP_MEMORY_SCOPE_AGENT);
                    p1 = __hip_atomic_load(a1, __ATOMIC_RELAXED, __HIP_MEMORY_SCOPE_AGENT);
                    unsigned long long ok =
                        __ballot((unsigned int)(p0 >> 32) == want) &
                        __ballot((unsigned int)(p1 >> 32) == want);
                    if (ok == 0xFFFFFFFFFFFFFFFFull) break;
                    __builtin_amdgcn_s_sleep(1);
                }
            }
            // stage swizzled: u = w*64+lane -> float4 a = w*16+(lane>>2), elem lane&3
            const int aa = w * 16 + (lane >> 2);
            const int fi = swz(aa) * 4 + (lane & 3);
            hstage[sl][0][fi] = __uint_as_float((unsigned int)p0);
            hstage[sl][1][fi] = __uint_as_float((unsigned int)p1);
        }
        // RAW barrier: order LDS (lgkmcnt) but let publish/out stores and
        // prefetch loads stay in flight (no vmcnt(0) drain).
        asm volatile("s_waitcnt lgkmcnt(0)" ::: "memory");
        __builtin_amdgcn_s_barrier();

        // ---- xp prefetch for s+1: issue load now, LDS-write after matvec ----
        float xpre = 0.f;
        const bool dopre = (tid < 128) && (tt + 1 < TC);
        if (dopre)
            xpre = E2[stok[tid >> 6][tt + 1] * UU + ug * 64 + (tid & 63)];

        // ---- matvec ONLY (pre-publish critical path kept minimal) ----
        float acc0[4] = {0.f, 0.f, 0.f, 0.f};
        float acc1[4] = {0.f, 0.f, 0.f, 0.f};
        if (s > 0) {
            const float* H0 = hstage[sl][0];
            const float* H1 = hstage[sl][1];
            #pragma unroll
            for (int g = 0; g < 4; ++g) {
                const int as2 = (4 * ks + g) ^ fmv;
                const float4 ha = *(const float4*)(H0 + as2 * 4);
                const float4 hc = *(const float4*)(H1 + as2 * 4);
                const float av[4] = {ha.x, ha.y, ha.z, ha.w};
                const float cv[4] = {hc.x, hc.y, hc.z, hc.w};
                #pragma unroll
                for (int m = 0; m < 4; ++m) {
                    const float4 wv = whb[(g * 4 + m) * 16];
                    acc0[0] = fmaf(av[m], wv.x, acc0[0]);
                    acc0[1] = fmaf(av[m], wv.y, acc0[1]);
                    acc0[2] = fmaf(av[m], wv.z, acc0[2]);
                    acc0[3] = fmaf(av[m], wv.w, acc0[3]);
                    acc1[0] = fmaf(cv[m], wv.x, acc1[0]);
                    acc1[1] = fmaf(cv[m], wv.y, acc1[1]);
                    acc1[2] = fmaf(cv[m], wv.z, acc1[2]);
                    acc1[3] = fmaf(cv[m], wv.w, acc1[3]);
                }
            }
        }
        // deferred xp LDS write (load latency hidden under matvec)
        if (dopre)
            xps[(s + 1) & 1][tid >> 6][tid & 63] = xpre;

        // ---- matvec fold-reduce: 8 vals over 32 ks-lanes in 9 shfls ----
        // (mappings verified in R7, absmax 6.1e-5) Result v in EVERY lane:
        // value (b=(ks>>4)&1, c=2*((ks>>3)&1)+((ks>>2)&1)).
        float tba[4];
        #pragma unroll
        for (int c = 0; c < 4; ++c) {
            const float x = (ks & 16) ? acc0[c] : acc1[c];
            const float y = __shfl_xor(x, 16, 64);
            tba[c] = ((ks & 16) ? acc1[c] : acc0[c]) + y;
        }
        float ua, ub;
        {
            const float x0 = (ks & 8) ? tba[0] : tba[2];
            const float x1 = (ks & 8) ? tba[1] : tba[3];
            const float y0 = __shfl_xor(x0, 8, 64);
            const float y1 = __shfl_xor(x1, 8, 64);
            ua = ((ks & 8) ? tba[2] : tba[0]) + y0;
            ub = ((ks & 8) ? tba[3] : tba[1]) + y1;
        }
        float v;
        {
            const float x = (ks & 4) ? ua : ub;
            const float y = __shfl_xor(x, 4, 64);
            v = ((ks & 4) ? ub : ua) + y;
        }
        v += __shfl_xor(v, 1, 64);
        v += __shfl_xor(v, 2, 64);

        // ---- finalize + publish h(s) ASAP: lanes (ks&3)==0 ----
        if ((ks & 3) == 0) {
            const int b = (ks >> 4) & 1;
            const int c = (((ks >> 3) & 1) << 1) | ((ks >> 2) & 1);
            const int u = quad * 4 + c;
            const float h = tanh_fast(v + xps[s & 1][b][u]);
            unsigned long long* dst =
                hpub + ((size_t)(s & 1) * BB + b0 + b) * UU + ug * 64 + u;
            const unsigned long long pk =
                ((unsigned long long)(unsigned int)s << 32) | __float_as_uint(h);
            *(volatile unsigned long long*)dst = pk;   // sc0 local-L2 copy
            __hip_atomic_store(dst, pk, __ATOMIC_RELAXED, __HIP_MEMORY_SCOPE_AGENT);
            hstage[s & 1][b][swz(ug * 16 + quad) * 4 + c] = h;
        }

        // ---- logits(s-1) AFTER publish: re-read staged h(s-1); this work
        //      hides inside the peers' exchange window (baseline's overlap) ----
        if (s > 0) {
            const float* H0 = hstage[sl][0];
            const float* H1 = hstage[sl][1];
            float s00 = 0.f, s01 = 0.f, s10 = 0.f, s11 = 0.f;
            #pragma unroll
            for (int g = 0; g < 4; ++g) {
                const int as2 = (4 * ks + g) ^ fmv;
                const float4 ha = *(const float4*)(H0 + as2 * 4);
                const float4 hc = *(const float4*)(H1 + as2 * 4);
                const float av[4] = {ha.x, ha.y, ha.z, ha.w};
                const float cv[4] = {hc.x, hc.y, hc.z, hc.w};
                #pragma unroll
                for (int m = 0; m < 4; ++m) {
                    s00 = fmaf(av[m], wdreg[4 * g + m],      s00);
                    s01 = fmaf(av[m], wdreg[16 + 4 * g + m], s01);
                    s10 = fmaf(cv[m], wdreg[4 * g + m],      s10);
                    s11 = fmaf(cv[m], wdreg[16 + 4 * g + m], s11);
                }
            }
            // logits fold-reduce: 4 vals over 32 lanes in 6 shfls
            float pa, pb;
            {
                const float x0 = (ks & 16) ? s00 : s10;
                const float x1 = (ks & 16) ? s01 : s11;
                const float y0 = __shfl_xor(x0, 16, 64);
                const float y1 = __shfl_xor(x1, 16, 64);
                pa = ((ks & 16) ? s10 : s00) + y0;
                pb = ((ks & 16) ? s11 : s01) + y1;
            }
            float L;
            {
                const float x = (ks & 8) ? pa : pb;
                const float y = __shfl_xor(x, 8, 64);
                L = ((ks & 8) ? pb : pa) + y;
            }
            L += __shfl_xor(L, 1, 64);
            L += __shfl_xor(L, 2, 64);
            L += __shfl_xor(L, 4, 64);
            if ((ks & 7) == 0) {
                const int b    = (ks >> 4) & 1;
                const int voff = (ks >> 3) & 1;
                out[((size_t)(b0 + b) * TT_ + (s - 1)) * VV + v0 + voff]
                    = L + (voff ? bdv1 : bdv0);
            }
        }
    }

    // ---- last chunk epilogue: logits(1023) needs full h(1023) staged ----
    if (last) {
        const int s  = t0 + TC - 1;          // 1023
        const int sl = s & 1;
        if (w != ug) {   // own slice already in hstage from tt=TC-1 finalize
            unsigned long long* a0 = hpub + ((size_t)sl * BB + b0) * UU + w * 64 + lane;
            unsigned long long* a1 = a0 + UU;
            volatile const unsigned long long* f0 = a0;
            volatile const unsigned long long* f1 = a1;
            const unsigned int want = (unsigned int)s;
            unsigned long long p0 = 0, p1 = 0;
            bool got = false;
            for (int it = 0; it < 24; ++it) {
                p0 = *f0; p1 = *f1;
                unsigned long long ok =
                    __ballot((unsigned int)(p0 >> 32) == want) &
                    __ballot((unsigned int)(p1 >> 32) == want);
                if (ok == 0xFFFFFFFFFFFFFFFFull) { got = true; break; }
            }
            if (!got) {
                while (true) {
                    p0 = __hip_atomic_load(a0, __ATOMIC_RELAXED, __HIP_MEMORY_SCOPE_AGENT);
                    p1 = __hip_atomic_load(a1, __ATOMIC_RELAXED, __HIP_MEMORY_SCOPE_AGENT);
                    unsigned long long ok =
                        __ballot((unsigned int)(p0 >> 32) == want) &
                        __ballot((unsigned int)(p1 >> 32) == want);
                    if (ok == 0xFFFFFFFFFFFFFFFFull) break;
                    __builtin_amdgcn_s_sleep(1);
                }
            }
            const int aa = w * 16 + (lane >> 2);
            const int fi = swz(aa) * 4 + (lane & 3);
            hstage[sl][0][fi] = __uint_as_float((unsigned int)p0);
            hstage[sl][1][fi] = __uint_as_float((unsigned int)p1);
        }
        __syncthreads();
        {
            const float* H0 = hstage[sl][0];
            const float* H1 = hstage[sl][1];
            float s00 = 0.f, s01 = 0.f, s10 = 0.f, s11 = 0.f;
            #pragma unroll
            for (int g = 0; g < 4; ++g) {
                const int as2 = (4 * ks + g) ^ fmv;
                const float4 ha = *(const float4*)(H0 + as2 * 4);
                const float4 hc = *(const float4*)(H1 + as2 * 4);
                const float av[4] = {ha.x, ha.y, ha.z, ha.w};
                const float cv[4] = {hc.x, hc.y, hc.z, hc.w};
                #pragma unroll
                for (int m = 0; m < 4; ++m) {
                    s00 = fmaf(av[m], wdreg[4 * g + m],      s00);
                    s01 = fmaf(av[m], wdreg[16 + 4 * g + m], s01);
                    s10 = fmaf(cv[m], wdreg[4 * g + m],      s10);
                    s11 = fmaf(cv[m], wdreg[16 + 4 * g + m], s11);
                }
            }
            float pa, pb;
            {
                const float x0 = (ks & 16) ? s00 : s10;
                const float x1 = (ks & 16) ? s01 : s11;
                const float y0 = __shfl_xor(x0, 16, 64);
                const float y1 = __shfl_xor(x1, 16, 64);
                pa = ((ks & 16) ? s10 : s00) + y0;
                pb = ((ks & 16) ? s11 : s01) + y1;
            }
            float L;
            {
                const float x = (ks & 8) ? pa : pb;
                const float y = __shfl_xor(x, 8, 64);
                L = ((ks & 8) ? pb : pa) + y;
            }
            L += __shfl_xor(L, 1, 64);
            L += __shfl_xor(L, 2, 64);
            L += __shfl_xor(L, 4, 64);
            if ((ks & 7) == 0) {
                const int b    = (ks >> 4) & 1;
                const int voff = (ks >> 3) & 1;
                out[((size_t)(b0 + b) * TT_ + s) * VV + v0 + voff]
                    = L + (voff ? bdv1 : bdv0);
            }
        }
    }
}

extern "C" void kernel_launch(void* const* d_in, const int* in_sizes, int n_in,
                              void* d_out, int out_size, void* d_ws, size_t ws_size,
                              hipStream_t stream)
{
    (void)in_sizes; (void)n_in; (void)ws_size; (void)out_size;

    const int*   toks = (const int*)  d_in[0];
    const float* emb  = (const float*)d_in[1];
    const float* Wx   = (const float*)d_in[2];
    const float* Wh   = (const float*)d_in[3];
    const float* bias = (const float*)d_in[4];
    const float* Wd   = (const float*)d_in[5];
    const float* bd   = (const float*)d_in[6];
    float* out = (float*)d_out;

    // ws layout: hpub [2*BB*UU] u64 (512 KB) | E2 [EE*UU] f32 (512 KB)
    unsigned long long* hpub = (unsigned long long*)d_ws;
    float* E2 = (float*)(hpub + 2 * BB * UU);

    // invalidate tags (0xFFFFFFFF matches no step) -> no stale-tag match on first run
    hipMemsetAsync(hpub, 0xFF, (size_t)(2 * BB * UU) * sizeof(unsigned long long), stream);
    e2_kernel<<<EE, UU, 0, stream>>>(emb, Wx, bias, E2);

    for (int c = 0; c < TT_ / TC; ++c) {
        const int t0 = c * TC;
        rnn_chunk_kernel<<<256, 512, 0, stream>>>(
            toks, E2, Wh, Wd, bd, hpub, out, t0, c == (TT_ / TC - 1));
    }
}

// Round 9
// 2360.758 us; speedup vs baseline: 1.6855x; 1.0605x over previous
//
#include <hip/hip_runtime.h>
#include <math.h>

#define BB   64      // batch
#define TT_  1024    // sequence length
#define UU   512     // hidden units
#define VV   256     // vocab (output)
#define EE   256     // embedding dim
#define TC   128     // time chunk (8 dispatches)

__device__ __forceinline__ float tanh_fast(float x) {
    // tanh(x) = 1 - 2/(e^{2x}+1); abs err ~1e-6 (validated: absmax 6e-5 end-to-end)
    float e = __expf(x + x);
    return 1.f - 2.f * __builtin_amdgcn_rcpf(e + 1.f);
}

// hstage float4-index swizzle (R4/R6-measured: SQ_LDS_BANK_CONFLICT == 0)
__device__ __forceinline__ int swz(int a) {
    return a ^ (((a >> 3) & 7) ^ ((a >> 6) & 1));
}

// ---------------- E2 = emb @ Wx + b : [256, 512] ----------------
__global__ __launch_bounds__(512) void e2_kernel(
    const float* __restrict__ emb, const float* __restrict__ Wx,
    const float* __restrict__ bias, float* __restrict__ E2)
{
    const int v = blockIdx.x;
    const int u = threadIdx.x;
    float acc = bias[u];
    const float* er = emb + v * EE;
    #pragma unroll 8
    for (int e = 0; e < EE; ++e)
        acc = fmaf(er[e], Wx[e * UU + u], acc);
    E2[v * UU + u] = acc;
}

// ---------------- fused recurrence + logits -------------------------------
// 256 blocks (1/CU), 512 thr = 8 waves. bg = bid&31 (2 batches), ug = bid>>5.
// Group-of-8 blocks (same bg) exchange h via hpub[(slot,b,u)] = (tag<<32|fp32),
// dual-published (volatile sc0 + agent atomic). Poll = baseline-proven: 24
// bounded sc0 rounds, then agent-scope spin with s_sleep (never hangs).
// R8 POST-MORTEM (6000cy/step): schedule overlap confirmed (417->318us). The
// dominant removable term is now Wh-from-LDS: 128 b128/step = the whole 128KB
// slice re-read every step (~1540cy at measured 85B/cy).
// R9: Wh -> VGPRs (whreg[16] f32, 64 regs, pinned via R4's scalar-asm idiom).
// WHY IT WON'T SPILL THIS TIME (R2/R4 lesson refined): those rounds had 10KB
// LDS -> RA targeted 2 blocks/CU -> ~128-VGPR budget -> spill at 88+96. This
// kernel keeps the 141KB WhL4 fill as an OCCUPANCY ANCHOR: hard 1 block/CU ->
// RA budget 256 VGPR. Diagnostic: VGPR_Count must rise to ~150; if <=110 the
// RA spilled and this line is dead.
// Schedule per step (R8's): poll h(s-1) -> stage -> lgkm-only barrier ->
// matvec (128 FMA from regs, 8 h b128) -> fold-reduce (9 shfl) -> tanh ->
// PUBLISH -> logits(s-1) from staged hstage (8 b128+64 FMA+6 shfl, hidden in
// exchange window). No atomics, no out memset.
__global__ __launch_bounds__(512)
void rnn_chunk_kernel(
    const int* __restrict__ toks, const float* __restrict__ E2,
    const float* __restrict__ Wh, const float* __restrict__ Wd,
    const float* __restrict__ bd,
    unsigned long long* hpub,     // [2][BB][UU] (tag,val) pairs
    float* out, int t0, int last)
{
    __shared__ __align__(16) float4 WhL4[8224];        // 128.5 KB (occupancy anchor)
    __shared__ __align__(16) float hstage[2][2][UU];   // 8 KB (swizzled)
    __shared__ __align__(16) float xps[2][2][64];      // 1 KB
    __shared__ int stok[2][TC];                        // 1 KB

    const int bid  = blockIdx.x;
    const int bg   = bid & 31;
    const int ug   = bid >> 5;
    const int tid  = threadIdx.x;
    const int w    = tid >> 6;
    const int lane = tid & 63;
    const int b0   = bg * 2;

    // roles: thread (quad, ks) does matvec units [ug*64+quad*4,+4) over
    // k [16ks,+16) AND logits v {ug*32+2quad, +1} over u [16ks,+16)
    const int qsel = lane >> 5;          // 0/1
    const int ks   = lane & 31;          // k/u slice [ks*16, +16)
    const int quad = w * 2 + qsel;       // [0,16)
    const int fmv  = ((ks >> 1) & 7) ^ ((ks >> 4) & 1);   // swz term, a = 4ks+g
    const int v0   = ug * 32 + quad * 2;

    // ---- Wh fragment -> registers (64 floats, f32 -- no numerics change) ----
    float4 whreg[16];                    // whreg[4g+m] = Wh[16ks+4g+m][ug*64+quad*4..+4]
    {
        const float4* Wh4 = (const float4*)Wh;   // [512][128]
        #pragma unroll
        for (int r = 0; r < 16; ++r)
            whreg[r] = Wh4[(ks * 16 + r) * 128 + ug * 16 + quad];
    }
    // pin via scalar temps (R4-proven compile): asm defs can't be remat'd from
    // the load -> whreg stays VGPR-resident (or spills VISIBLY to scratch).
    #pragma unroll
    for (int r = 0; r < 16; ++r) {
        float px = whreg[r].x, py = whreg[r].y, pz = whreg[r].z, pw = whreg[r].w;
        asm volatile("" : "+v"(px), "+v"(py), "+v"(pz), "+v"(pw));
        whreg[r] = make_float4(px, py, pz, pw);
    }

    // ---- Wd column pair -> registers (32 floats) ----
    float wdreg[32];                     // [j]=Wd[16ks+j][v0], [16+j]=..[v0+1]
    #pragma unroll
    for (int j = 0; j < 16; ++j) {
        const float2 wd2 = *(const float2*)(Wd + (ks * 16 + j) * VV + v0);
        wdreg[j]      = wd2.x;
        wdreg[16 + j] = wd2.y;
    }
    const float bdv0 = bd[v0];
    const float bdv1 = bd[v0 + 1];

    // ---- Wh slice -> LDS: OCCUPANCY ANCHOR (141KB -> 1 block/CU -> RA budget
    //      256 VGPR). Filled once (also a warm fallback copy); matvec reads
    //      registers. Removing this fill shrinks LDS and re-triggers the
    //      R2/R4 spill -- do not remove. ----
    {
        const int kw = tid >> 4, qw = tid & 15;
        const float4* Wh4 = (const float4*)Wh;   // [512][128]
        #pragma unroll
        for (int r = 0; r < 16; ++r)
            WhL4[kw * 257 + r * 16 + qw] = Wh4[(kw * 16 + r) * 128 + ug * 16 + qw];
    }

    // ---- chunk tokens + xp(t0) staging ----
    if (tid < 256) {
        const int b = tid >> 7, q = tid & 127;
        stok[b][q] = toks[(b0 + b) * TT_ + t0 + q];
    }
    if (tid < 128) {
        const int b = tid >> 6, u = tid & 63;
        xps[0][b][u] = E2[toks[(b0 + b) * TT_ + t0] * UU + ug * 64 + u];
    }
    __syncthreads();

    for (int tt = 0; tt < TC; ++tt) {
        const int s  = t0 + tt;
        const int sl = (s - 1) & 1;

        // ---- poll h(s-1) (skip own slice except at chunk start) ----
        if (s > 0 && (w != ug || tt == 0)) {
            unsigned long long* a0 = hpub + ((size_t)sl * BB + b0) * UU + w * 64 + lane;
            unsigned long long* a1 = a0 + UU;
            volatile const unsigned long long* f0 = a0;
            volatile const unsigned long long* f1 = a1;
            const unsigned int want = (unsigned int)(s - 1);
            unsigned long long p0 = 0, p1 = 0;
            bool got = false;
            for (int it = 0; it < 24; ++it) {     // sc0 fast rounds (local-XCD L2)
                p0 = *f0; p1 = *f1;
                unsigned long long ok =
                    __ballot((unsigned int)(p0 >> 32) == want) &
                    __ballot((unsigned int)(p1 >> 32) == want);
                if (ok == 0xFFFFFFFFFFFFFFFFull) { got = true; break; }
            }
            if (!got) {                           // proven agent-scope fallback
                while (true) {
                    p0 = __hip_atomic_load(a0, __ATOMIC_RELAXED, __HIP_MEMORY_SCOPE_AGENT);
                    p1 = __hip_atomic_load(a1, __ATOMIC_RELAXED, __HIP_MEMORY_SCOPE_AGENT);
                    unsigned long long ok =
                        __ballot((unsigned int)(p0 >> 32) == want) &
                        __ballot((unsigned int)(p1 >> 32) == want);
                    if (ok == 0xFFFFFFFFFFFFFFFFull) break;
                    __builtin_amdgcn_s_sleep(1);
                }
            }
            // stage swizzled: u = w*64+lane -> float4 a = w*16+(lane>>2), elem lane&3
            const int aa = w * 16 + (lane >> 2);
            const int fi = swz(aa) * 4 + (lane & 3);
            hstage[sl][0][fi] = __uint_as_float((unsigned int)p0);
            hstage[sl][1][fi] = __uint_as_float((unsigned int)p1);
        }
        // RAW barrier: order LDS (lgkmcnt) but let publish/out stores and
        // prefetch loads stay in flight (no vmcnt(0) drain).
        asm volatile("s_waitcnt lgkmcnt(0)" ::: "memory");
        __builtin_amdgcn_s_barrier();

        // ---- xp prefetch for s+1: issue load now, LDS-write after matvec ----
        float xpre = 0.f;
        const bool dopre = (tid < 128) && (tt + 1 < TC);
        if (dopre)
            xpre = E2[stok[tid >> 6][tt + 1] * UU + ug * 64 + (tid & 63)];

        // ---- matvec from REGISTERS; h(s-1) from swizzled LDS (8 b128) ----
        float acc0[4] = {0.f, 0.f, 0.f, 0.f};
        float acc1[4] = {0.f, 0.f, 0.f, 0.f};
        if (s > 0) {
            const float* H0 = hstage[sl][0];
            const float* H1 = hstage[sl][1];
            #pragma unroll
            for (int g = 0; g < 4; ++g) {
                const int as2 = (4 * ks + g) ^ fmv;
                const float4 ha = *(const float4*)(H0 + as2 * 4);
                const float4 hc = *(const float4*)(H1 + as2 * 4);
                const float av[4] = {ha.x, ha.y, ha.z, ha.w};
                const float cv[4] = {hc.x, hc.y, hc.z, hc.w};
                #pragma unroll
                for (int m = 0; m < 4; ++m) {
                    const float4 wv = whreg[g * 4 + m];
                    acc0[0] = fmaf(av[m], wv.x, acc0[0]);
                    acc0[1] = fmaf(av[m], wv.y, acc0[1]);
                    acc0[2] = fmaf(av[m], wv.z, acc0[2]);
                    acc0[3] = fmaf(av[m], wv.w, acc0[3]);
                    acc1[0] = fmaf(cv[m], wv.x, acc1[0]);
                    acc1[1] = fmaf(cv[m], wv.y, acc1[1]);
                    acc1[2] = fmaf(cv[m], wv.z, acc1[2]);
                    acc1[3] = fmaf(cv[m], wv.w, acc1[3]);
                }
            }
        }
        // deferred xp LDS write (load latency hidden under matvec)
        if (dopre)
            xps[(s + 1) & 1][tid >> 6][tid & 63] = xpre;

        // ---- matvec fold-reduce: 8 vals over 32 ks-lanes in 9 shfls ----
        // (mappings verified R7/R8, absmax 6.1e-5) Result v in EVERY lane:
        // value (b=(ks>>4)&1, c=2*((ks>>3)&1)+((ks>>2)&1)).
        float tba[4];
        #pragma unroll
        for (int c = 0; c < 4; ++c) {
            const float x = (ks & 16) ? acc0[c] : acc1[c];
            const float y = __shfl_xor(x, 16, 64);
            tba[c] = ((ks & 16) ? acc1[c] : acc0[c]) + y;
        }
        float ua, ub;
        {
            const float x0 = (ks & 8) ? tba[0] : tba[2];
            const float x1 = (ks & 8) ? tba[1] : tba[3];
            const float y0 = __shfl_xor(x0, 8, 64);
            const float y1 = __shfl_xor(x1, 8, 64);
            ua = ((ks & 8) ? tba[2] : tba[0]) + y0;
            ub = ((ks & 8) ? tba[3] : tba[1]) + y1;
        }
        float v;
        {
            const float x = (ks & 4) ? ua : ub;
            const float y = __shfl_xor(x, 4, 64);
            v = ((ks & 4) ? ub : ua) + y;
        }
        v += __shfl_xor(v, 1, 64);
        v += __shfl_xor(v, 2, 64);

        // ---- finalize + publish h(s) ASAP: lanes (ks&3)==0 ----
        if ((ks & 3) == 0) {
            const int b = (ks >> 4) & 1;
            const int c = (((ks >> 3) & 1) << 1) | ((ks >> 2) & 1);
            const int u = quad * 4 + c;
            const float h = tanh_fast(v + xps[s & 1][b][u]);
            unsigned long long* dst =
                hpub + ((size_t)(s & 1) * BB + b0 + b) * UU + ug * 64 + u;
            const unsigned long long pk =
                ((unsigned long long)(unsigned int)s << 32) | __float_as_uint(h);
            *(volatile unsigned long long*)dst = pk;   // sc0 local-L2 copy
            __hip_atomic_store(dst, pk, __ATOMIC_RELAXED, __HIP_MEMORY_SCOPE_AGENT);
            hstage[s & 1][b][swz(ug * 16 + quad) * 4 + c] = h;
        }

        // ---- logits(s-1) AFTER publish: re-read staged h(s-1); hidden in
        //      the peers' exchange window (R8-proven overlap) ----
        if (s > 0) {
            const float* H0 = hstage[sl][0];
            const float* H1 = hstage[sl][1];
            float s00 = 0.f, s01 = 0.f, s10 = 0.f, s11 = 0.f;
            #pragma unroll
            for (int g = 0; g < 4; ++g) {
                const int as2 = (4 * ks + g) ^ fmv;
                const float4 ha = *(const float4*)(H0 + as2 * 4);
                const float4 hc = *(const float4*)(H1 + as2 * 4);
                const float av[4] = {ha.x, ha.y, ha.z, ha.w};
                const float cv[4] = {hc.x, hc.y, hc.z, hc.w};
                #pragma unroll
                for (int m = 0; m < 4; ++m) {
                    s00 = fmaf(av[m], wdreg[4 * g + m],      s00);
                    s01 = fmaf(av[m], wdreg[16 + 4 * g + m], s01);
                    s10 = fmaf(cv[m], wdreg[4 * g + m],      s10);
                    s11 = fmaf(cv[m], wdreg[16 + 4 * g + m], s11);
                }
            }
            // logits fold-reduce: 4 vals over 32 lanes in 6 shfls
            float pa, pb;
            {
                const float x0 = (ks & 16) ? s00 : s10;
                const float x1 = (ks & 16) ? s01 : s11;
                const float y0 = __shfl_xor(x0, 16, 64);
                const float y1 = __shfl_xor(x1, 16, 64);
                pa = ((ks & 16) ? s10 : s00) + y0;
                pb = ((ks & 16) ? s11 : s01) + y1;
            }
            float L;
            {
                const float x = (ks & 8) ? pa : pb;
                const float y = __shfl_xor(x, 8, 64);
                L = ((ks & 8) ? pb : pa) + y;
            }
            L += __shfl_xor(L, 1, 64);
            L += __shfl_xor(L, 2, 64);
            L += __shfl_xor(L, 4, 64);
            if ((ks & 7) == 0) {
                const int b    = (ks >> 4) & 1;
                const int voff = (ks >> 3) & 1;
                out[((size_t)(b0 + b) * TT_ + (s - 1)) * VV + v0 + voff]
                    = L + (voff ? bdv1 : bdv0);
            }
        }
    }

    // ---- last chunk epilogue: logits(1023) needs full h(1023) staged ----
    if (last) {
        const int s  = t0 + TC - 1;          // 1023
        const int sl = s & 1;
        if (w != ug) {   // own slice already in hstage from tt=TC-1 finalize
            unsigned long long* a0 = hpub + ((size_t)sl * BB + b0) * UU + w * 64 + lane;
            unsigned long long* a1 = a0 + UU;
            volatile const unsigned long long* f0 = a0;
            volatile const unsigned long long* f1 = a1;
            const unsigned int want = (unsigned int)s;
            unsigned long long p0 = 0, p1 = 0;
            bool got = false;
            for (int it = 0; it < 24; ++it) {
                p0 = *f0; p1 = *f1;
                unsigned long long ok =
                    __ballot((unsigned int)(p0 >> 32) == want) &
                    __ballot((unsigned int)(p1 >> 32) == want);
                if (ok == 0xFFFFFFFFFFFFFFFFull) { got = true; break; }
            }
            if (!got) {
                while (true) {
                    p0 = __hip_atomic_load(a0, __ATOMIC_RELAXED, __HIP_MEMORY_SCOPE_AGENT);
                    p1 = __hip_atomic_load(a1, __ATOMIC_RELAXED, __HIP_MEMORY_SCOPE_AGENT);
                    unsigned long long ok =
                        __ballot((unsigned int)(p0 >> 32) == want) &
                        __ballot((unsigned int)(p1 >> 32) == want);
                    if (ok == 0xFFFFFFFFFFFFFFFFull) break;
                    __builtin_amdgcn_s_sleep(1);
                }
            }
            const int aa = w * 16 + (lane >> 2);
            const int fi = swz(aa) * 4 + (lane & 3);
            hstage[sl][0][fi] = __uint_as_float((unsigned int)p0);
            hstage[sl][1][fi] = __uint_as_float((unsigned int)p1);
        }
        __syncthreads();
        {
            const float* H0 = hstage[sl][0];
            const float* H1 = hstage[sl][1];
            float s00 = 0.f, s01 = 0.f, s10 = 0.f, s11 = 0.f;
            #pragma unroll
            for (int g = 0; g < 4; ++g) {
                const int as2 = (4 * ks + g) ^ fmv;
                const float4 ha = *(const float4*)(H0 + as2 * 4);
                const float4 hc = *(const float4*)(H1 + as2 * 4);
                const float av[4] = {ha.x, ha.y, ha.z, ha.w};
                const float cv[4] = {hc.x, hc.y, hc.z, hc.w};
                #pragma unroll
                for (int m = 0; m < 4; ++m) {
                    s00 = fmaf(av[m], wdreg[4 * g + m],      s00);
                    s01 = fmaf(av[m], wdreg[16 + 4 * g + m], s01);
                    s10 = fmaf(cv[m], wdreg[4 * g + m],      s10);
                    s11 = fmaf(cv[m], wdreg[16 + 4 * g + m], s11);
                }
            }
            float pa, pb;
            {
                const float x0 = (ks & 16) ? s00 : s10;
                const float x1 = (ks & 16) ? s01 : s11;
                const float y0 = __shfl_xor(x0, 16, 64);
                const float y1 = __shfl_xor(x1, 16, 64);
                pa = ((ks & 16) ? s10 : s00) + y0;
                pb = ((ks & 16) ? s11 : s01) + y1;
            }
            float L;
            {
                const float x = (ks & 8) ? pa : pb;
                const float y = __shfl_xor(x, 8, 64);
                L = ((ks & 8) ? pb : pa) + y;
            }
            L += __shfl_xor(L, 1, 64);
            L += __shfl_xor(L, 2, 64);
            L += __shfl_xor(L, 4, 64);
            if ((ks & 7) == 0) {
                const int b    = (ks >> 4) & 1;
                const int voff = (ks >> 3) & 1;
                out[((size_t)(b0 + b) * TT_ + s) * VV + v0 + voff]
                    = L + (voff ? bdv1 : bdv0);
            }
        }
    }
}

extern "C" void kernel_launch(void* const* d_in, const int* in_sizes, int n_in,
                              void* d_out, int out_size, void* d_ws, size_t ws_size,
                              hipStream_t stream)
{
    (void)in_sizes; (void)n_in; (void)ws_size; (void)out_size;

    const int*   toks = (const int*)  d_in[0];
    const float* emb  = (const float*)d_in[1];
    const float* Wx   = (const float*)d_in[2];
    const float* Wh   = (const float*)d_in[3];
    const float* bias = (const float*)d_in[4];
    const float* Wd   = (const float*)d_in[5];
    const float* bd   = (const float*)d_in[6];
    float* out = (float*)d_out;

    // ws layout: hpub [2*BB*UU] u64 (512 KB) | E2 [EE*UU] f32 (512 KB)
    unsigned long long* hpub = (unsigned long long*)d_ws;
    float* E2 = (float*)(hpub + 2 * BB * UU);

    // invalidate tags (0xFFFFFFFF matches no step) -> no stale-tag match on first run
    hipMemsetAsync(hpub, 0xFF, (size_t)(2 * BB * UU) * sizeof(unsigned long long), stream);
    e2_kernel<<<EE, UU, 0, stream>>>(emb, Wx, bias, E2);

    for (int c = 0; c < TT_ / TC; ++c) {
        const int t0 = c * TC;
        rnn_chunk_kernel<<<256, 512, 0, stream>>>(
            toks, E2, Wh, Wd, bd, hpub, out, t0, c == (TT_ / TC - 1));
    }
}

// Round 10
// 2271.629 us; speedup vs baseline: 1.7516x; 1.0392x over previous
//
#include <hip/hip_runtime.h>
#include <math.h>

#define BB   64      // batch
#define TT_  1024    // sequence length
#define UU   512     // hidden units
#define VV   256     // vocab (output)
#define EE   256     // embedding dim
#define TC   128     // time chunk (8 dispatches)

__device__ __forceinline__ float tanh_fast(float x) {
    // tanh(x) = 1 - 2/(e^{2x}+1); abs err ~1e-6 (validated: absmax 6e-5 end-to-end)
    float e = __expf(x + x);
    return 1.f - 2.f * __builtin_amdgcn_rcpf(e + 1.f);
}

// hstage float4-index swizzle (R4/R6-measured: SQ_LDS_BANK_CONFLICT == 0)
__device__ __forceinline__ int swz(int a) {
    return a ^ (((a >> 3) & 7) ^ ((a >> 6) & 1));
}

// ---------------- E2 = emb @ Wx + b : [256, 512] ----------------
__global__ __launch_bounds__(512) void e2_kernel(
    const float* __restrict__ emb, const float* __restrict__ Wx,
    const float* __restrict__ bias, float* __restrict__ E2)
{
    const int v = blockIdx.x;
    const int u = threadIdx.x;
    float acc = bias[u];
    const float* er = emb + v * EE;
    #pragma unroll 8
    for (int e = 0; e < EE; ++e)
        acc = fmaf(er[e], Wx[e * UU + u], acc);
    E2[v * UU + u] = acc;
}

// ---------------- fused recurrence + logits -------------------------------
// 256 blocks (1/CU), 512 thr = 8 waves. bg = bid&31 (2 batches), ug = bid>>5.
// Group-of-8 blocks (same bg, same XCD under round-robin: bids == bg mod 8)
// exchange h via hpub[(slot,b,u)] = (tag<<32|fp32), dual-published (volatile
// sc0 + agent atomic). Poll = baseline-proven: 24 bounded sc0 rounds, then
// agent-scope spin with s_sleep (never hangs).
// R9 POST-MORTEM: WhL4 anchor was DCE'd (LDS=10KB), VGPR=84 -> whreg/wdreg in
// SCRATCH, and it still improved (318->301us): the win was moving Wh traffic
// OFF the DS pipe (vmem/L1/L2 runs parallel to LDS unit). Register-residency
// line is triple-falsified -- accept scratch Wh; the RA's choice measured best.
// R10: logits h re-read was byte-identical to matvec's h read (same as2 =
// 4ks+g fragments). SAVE the 32 h values in regs during matvec; logits after
// publish reuses them -> logits' 8 b128/lane/step of DS gone (-770cy/CU),
// publish stays earliest (R7 lesson), post-publish work = pure VALU+shfl
// hidden in the exchange window.
// Schedule per step: poll h(s-1) -> stage -> lgkm-only barrier -> matvec
// (128 FMA, 8 h b128, h saved to regs) -> fold-reduce (9 shfl) -> tanh ->
// PUBLISH -> logits(s-1) from saved regs (64 FMA + 6 shfl + store, hidden in
// exchange window). No atomics, no out memset.
__global__ __launch_bounds__(512)
void rnn_chunk_kernel(
    const int* __restrict__ toks, const float* __restrict__ E2,
    const float* __restrict__ Wh, const float* __restrict__ Wd,
    const float* __restrict__ bd,
    unsigned long long* hpub,     // [2][BB][UU] (tag,val) pairs
    float* out, int t0, int last)
{
    __shared__ __align__(16) float hstage[2][2][UU];   // 8 KB (swizzled)
    __shared__ __align__(16) float xps[2][2][64];      // 1 KB
    __shared__ int stok[2][TC];                        // 1 KB

    const int bid  = blockIdx.x;
    const int bg   = bid & 31;
    const int ug   = bid >> 5;
    const int tid  = threadIdx.x;
    const int w    = tid >> 6;
    const int lane = tid & 63;
    const int b0   = bg * 2;

    // roles: thread (quad, ks) does matvec units [ug*64+quad*4,+4) over
    // k [16ks,+16) AND logits v {ug*32+2quad, +1} over u [16ks,+16)
    const int qsel = lane >> 5;          // 0/1
    const int ks   = lane & 31;          // k/u slice [ks*16, +16)
    const int quad = w * 2 + qsel;       // [0,16)
    const int fmv  = ((ks >> 1) & 7) ^ ((ks >> 4) & 1);   // swz term, a = 4ks+g
    const int v0   = ug * 32 + quad * 2;

    // ---- Wh fragment (RA keeps in scratch -- measured best; vmem pipe
    //      overlaps the DS pipe, which is the real constraint) ----
    float4 whreg[16];                    // whreg[4g+m] = Wh[16ks+4g+m][ug*64+quad*4..+4]
    {
        const float4* Wh4 = (const float4*)Wh;   // [512][128]
        #pragma unroll
        for (int r = 0; r < 16; ++r)
            whreg[r] = Wh4[(ks * 16 + r) * 128 + ug * 16 + quad];
    }
    #pragma unroll
    for (int r = 0; r < 16; ++r) {
        float px = whreg[r].x, py = whreg[r].y, pz = whreg[r].z, pw = whreg[r].w;
        asm volatile("" : "+v"(px), "+v"(py), "+v"(pz), "+v"(pw));
        whreg[r] = make_float4(px, py, pz, pw);
    }

    // ---- Wd column pair -> registers/scratch (32 floats) ----
    float wdreg[32];                     // [j]=Wd[16ks+j][v0], [16+j]=..[v0+1]
    #pragma unroll
    for (int j = 0; j < 16; ++j) {
        const float2 wd2 = *(const float2*)(Wd + (ks * 16 + j) * VV + v0);
        wdreg[j]      = wd2.x;
        wdreg[16 + j] = wd2.y;
    }
    const float bdv0 = bd[v0];
    const float bdv1 = bd[v0 + 1];

    // ---- chunk tokens + xp(t0) staging ----
    if (tid < 256) {
        const int b = tid >> 7, q = tid & 127;
        stok[b][q] = toks[(b0 + b) * TT_ + t0 + q];
    }
    if (tid < 128) {
        const int b = tid >> 6, u = tid & 63;
        xps[0][b][u] = E2[toks[(b0 + b) * TT_ + t0] * UU + ug * 64 + u];
    }
    __syncthreads();

    for (int tt = 0; tt < TC; ++tt) {
        const int s  = t0 + tt;
        const int sl = (s - 1) & 1;

        // ---- poll h(s-1) (skip own slice except at chunk start) ----
        if (s > 0 && (w != ug || tt == 0)) {
            unsigned long long* a0 = hpub + ((size_t)sl * BB + b0) * UU + w * 64 + lane;
            unsigned long long* a1 = a0 + UU;
            volatile const unsigned long long* f0 = a0;
            volatile const unsigned long long* f1 = a1;
            const unsigned int want = (unsigned int)(s - 1);
            unsigned long long p0 = 0, p1 = 0;
            bool got = false;
            for (int it = 0; it < 24; ++it) {     // sc0 fast rounds (local-XCD L2)
                p0 = *f0; p1 = *f1;
                unsigned long long ok =
                    __ballot((unsigned int)(p0 >> 32) == want) &
                    __ballot((unsigned int)(p1 >> 32) == want);
                if (ok == 0xFFFFFFFFFFFFFFFFull) { got = true; break; }
            }
            if (!got) {                           // proven agent-scope fallback
                while (true) {
                    p0 = __hip_atomic_load(a0, __ATOMIC_RELAXED, __HIP_MEMORY_SCOPE_AGENT);
                    p1 = __hip_atomic_load(a1, __ATOMIC_RELAXED, __HIP_MEMORY_SCOPE_AGENT);
                    unsigned long long ok =
                        __ballot((unsigned int)(p0 >> 32) == want) &
                        __ballot((unsigned int)(p1 >> 32) == want);
                    if (ok == 0xFFFFFFFFFFFFFFFFull) break;
                    __builtin_amdgcn_s_sleep(1);
                }
            }
            // stage swizzled: u = w*64+lane -> float4 a = w*16+(lane>>2), elem lane&3
            const int aa = w * 16 + (lane >> 2);
            const int fi = swz(aa) * 4 + (lane & 3);
            hstage[sl][0][fi] = __uint_as_float((unsigned int)p0);
            hstage[sl][1][fi] = __uint_as_float((unsigned int)p1);
        }
        // RAW barrier: order LDS (lgkmcnt) but let publish/out stores and
        // prefetch loads stay in flight (no vmcnt(0) drain).
        asm volatile("s_waitcnt lgkmcnt(0)" ::: "memory");
        __builtin_amdgcn_s_barrier();

        // ---- xp prefetch for s+1: issue load now, LDS-write after matvec ----
        float xpre = 0.f;
        const bool dopre = (tid < 128) && (tt + 1 < TC);
        if (dopre)
            xpre = E2[stok[tid >> 6][tt + 1] * UU + ug * 64 + (tid & 63)];

        // ---- matvec; h(s-1) fragments read ONCE from LDS, SAVED to regs ----
        float acc0[4] = {0.f, 0.f, 0.f, 0.f};
        float acc1[4] = {0.f, 0.f, 0.f, 0.f};
        float hsv0[16], hsv1[16];        // saved h fragments (const-idx after unroll)
        if (s > 0) {
            const float* H0 = hstage[sl][0];
            const float* H1 = hstage[sl][1];
            #pragma unroll
            for (int g = 0; g < 4; ++g) {
                const int as2 = (4 * ks + g) ^ fmv;
                const float4 ha = *(const float4*)(H0 + as2 * 4);
                const float4 hc = *(const float4*)(H1 + as2 * 4);
                const float av[4] = {ha.x, ha.y, ha.z, ha.w};
                const float cv[4] = {hc.x, hc.y, hc.z, hc.w};
                #pragma unroll
                for (int m = 0; m < 4; ++m) {
                    hsv0[g * 4 + m] = av[m];
                    hsv1[g * 4 + m] = cv[m];
                    const float4 wv = whreg[g * 4 + m];
                    acc0[0] = fmaf(av[m], wv.x, acc0[0]);
                    acc0[1] = fmaf(av[m], wv.y, acc0[1]);
                    acc0[2] = fmaf(av[m], wv.z, acc0[2]);
                    acc0[3] = fmaf(av[m], wv.w, acc0[3]);
                    acc1[0] = fmaf(cv[m], wv.x, acc1[0]);
                    acc1[1] = fmaf(cv[m], wv.y, acc1[1]);
                    acc1[2] = fmaf(cv[m], wv.z, acc1[2]);
                    acc1[3] = fmaf(cv[m], wv.w, acc1[3]);
                }
            }
        }
        // deferred xp LDS write (load latency hidden under matvec)
        if (dopre)
            xps[(s + 1) & 1][tid >> 6][tid & 63] = xpre;

        // ---- matvec fold-reduce: 8 vals over 32 ks-lanes in 9 shfls ----
        // (mappings verified R7/R8, absmax 6.1e-5) Result v in EVERY lane:
        // value (b=(ks>>4)&1, c=2*((ks>>3)&1)+((ks>>2)&1)).
        float tba[4];
        #pragma unroll
        for (int c = 0; c < 4; ++c) {
            const float x = (ks & 16) ? acc0[c] : acc1[c];
            const float y = __shfl_xor(x, 16, 64);
            tba[c] = ((ks & 16) ? acc1[c] : acc0[c]) + y;
        }
        float ua, ub;
        {
            const float x0 = (ks & 8) ? tba[0] : tba[2];
            const float x1 = (ks & 8) ? tba[1] : tba[3];
            const float y0 = __shfl_xor(x0, 8, 64);
            const float y1 = __shfl_xor(x1, 8, 64);
            ua = ((ks & 8) ? tba[2] : tba[0]) + y0;
            ub = ((ks & 8) ? tba[3] : tba[1]) + y1;
        }
        float v;
        {
            const float x = (ks & 4) ? ua : ub;
            const float y = __shfl_xor(x, 4, 64);
            v = ((ks & 4) ? ub : ua) + y;
        }
        v += __shfl_xor(v, 1, 64);
        v += __shfl_xor(v, 2, 64);

        // ---- finalize + publish h(s) ASAP: lanes (ks&3)==0 ----
        if ((ks & 3) == 0) {
            const int b = (ks >> 4) & 1;
            const int c = (((ks >> 3) & 1) << 1) | ((ks >> 2) & 1);
            const int u = quad * 4 + c;
            const float h = tanh_fast(v + xps[s & 1][b][u]);
            unsigned long long* dst =
                hpub + ((size_t)(s & 1) * BB + b0 + b) * UU + ug * 64 + u;
            const unsigned long long pk =
                ((unsigned long long)(unsigned int)s << 32) | __float_as_uint(h);
            *(volatile unsigned long long*)dst = pk;   // sc0 local-L2 copy
            __hip_atomic_store(dst, pk, __ATOMIC_RELAXED, __HIP_MEMORY_SCOPE_AGENT);
            hstage[s & 1][b][swz(ug * 16 + quad) * 4 + c] = h;
        }

        // ---- logits(s-1) AFTER publish, from SAVED regs (no LDS reads);
        //      hidden in the peers' exchange window (R8-proven overlap) ----
        if (s > 0) {
            float s00 = 0.f, s01 = 0.f, s10 = 0.f, s11 = 0.f;
            #pragma unroll
            for (int g = 0; g < 4; ++g) {
                #pragma unroll
                for (int m = 0; m < 4; ++m) {
                    s00 = fmaf(hsv0[g * 4 + m], wdreg[4 * g + m],      s00);
                    s01 = fmaf(hsv0[g * 4 + m], wdreg[16 + 4 * g + m], s01);
                    s10 = fmaf(hsv1[g * 4 + m], wdreg[4 * g + m],      s10);
                    s11 = fmaf(hsv1[g * 4 + m], wdreg[16 + 4 * g + m], s11);
                }
            }
            // logits fold-reduce: 4 vals over 32 lanes in 6 shfls
            float pa, pb;
            {
                const float x0 = (ks & 16) ? s00 : s10;
                const float x1 = (ks & 16) ? s01 : s11;
                const float y0 = __shfl_xor(x0, 16, 64);
                const float y1 = __shfl_xor(x1, 16, 64);
                pa = ((ks & 16) ? s10 : s00) + y0;
                pb = ((ks & 16) ? s11 : s01) + y1;
            }
            float L;
            {
                const float x = (ks & 8) ? pa : pb;
                const float y = __shfl_xor(x, 8, 64);
                L = ((ks & 8) ? pb : pa) + y;
            }
            L += __shfl_xor(L, 1, 64);
            L += __shfl_xor(L, 2, 64);
            L += __shfl_xor(L, 4, 64);
            if ((ks & 7) == 0) {
                const int b    = (ks >> 4) & 1;
                const int voff = (ks >> 3) & 1;
                out[((size_t)(b0 + b) * TT_ + (s - 1)) * VV + v0 + voff]
                    = L + (voff ? bdv1 : bdv0);
            }
        }
    }

    // ---- last chunk epilogue: logits(1023) needs full h(1023) staged ----
    if (last) {
        const int s  = t0 + TC - 1;          // 1023
        const int sl = s & 1;
        if (w != ug) {   // own slice already in hstage from tt=TC-1 finalize
            unsigned long long* a0 = hpub + ((size_t)sl * BB + b0) * UU + w * 64 + lane;
            unsigned long long* a1 = a0 + UU;
            volatile const unsigned long long* f0 = a0;
            volatile const unsigned long long* f1 = a1;
            const unsigned int want = (unsigned int)s;
            unsigned long long p0 = 0, p1 = 0;
            bool got = false;
            for (int it = 0; it < 24; ++it) {
                p0 = *f0; p1 = *f1;
                unsigned long long ok =
                    __ballot((unsigned int)(p0 >> 32) == want) &
                    __ballot((unsigned int)(p1 >> 32) == want);
                if (ok == 0xFFFFFFFFFFFFFFFFull) { got = true; break; }
            }
            if (!got) {
                while (true) {
                    p0 = __hip_atomic_load(a0, __ATOMIC_RELAXED, __HIP_MEMORY_SCOPE_AGENT);
                    p1 = __hip_atomic_load(a1, __ATOMIC_RELAXED, __HIP_MEMORY_SCOPE_AGENT);
                    unsigned long long ok =
                        __ballot((unsigned int)(p0 >> 32) == want) &
                        __ballot((unsigned int)(p1 >> 32) == want);
                    if (ok == 0xFFFFFFFFFFFFFFFFull) break;
                    __builtin_amdgcn_s_sleep(1);
                }
            }
            const int aa = w * 16 + (lane >> 2);
            const int fi = swz(aa) * 4 + (lane & 3);
            hstage[sl][0][fi] = __uint_as_float((unsigned int)p0);
            hstage[sl][1][fi] = __uint_as_float((unsigned int)p1);
        }
        __syncthreads();
        {
            const float* H0 = hstage[sl][0];
            const float* H1 = hstage[sl][1];
            float s00 = 0.f, s01 = 0.f, s10 = 0.f, s11 = 0.f;
            #pragma unroll
            for (int g = 0; g < 4; ++g) {
                const int as2 = (4 * ks + g) ^ fmv;
                const float4 ha = *(const float4*)(H0 + as2 * 4);
                const float4 hc = *(const float4*)(H1 + as2 * 4);
                const float av[4] = {ha.x, ha.y, ha.z, ha.w};
                const float cv[4] = {hc.x, hc.y, hc.z, hc.w};
                #pragma unroll
                for (int m = 0; m < 4; ++m) {
                    s00 = fmaf(av[m], wdreg[4 * g + m],      s00);
                    s01 = fmaf(av[m], wdreg[16 + 4 * g + m], s01);
                    s10 = fmaf(cv[m], wdreg[4 * g + m],      s10);
                    s11 = fmaf(cv[m], wdreg[16 + 4 * g + m], s11);
                }
            }
            float pa, pb;
            {
                const float x0 = (ks & 16) ? s00 : s10;
                const float x1 = (ks & 16) ? s01 : s11;
                const float y0 = __shfl_xor(x0, 16, 64);
                const float y1 = __shfl_xor(x1, 16, 64);
                pa = ((ks & 16) ? s10 : s00) + y0;
                pb = ((ks & 16) ? s11 : s01) + y1;
            }
            float L;
            {
                const float x = (ks & 8) ? pa : pb;
                const float y = __shfl_xor(x, 8, 64);
                L = ((ks & 8) ? pb : pa) + y;
            }
            L += __shfl_xor(L, 1, 64);
            L += __shfl_xor(L, 2, 64);
            L += __shfl_xor(L, 4, 64);
            if ((ks & 7) == 0) {
                const int b    = (ks >> 4) & 1;
                const int voff = (ks >> 3) & 1;
                out[((size_t)(b0 + b) * TT_ + s) * VV + v0 + voff]
                    = L + (voff ? bdv1 : bdv0);
            }
        }
    }
}

extern "C" void kernel_launch(void* const* d_in, const int* in_sizes, int n_in,
                              void* d_out, int out_size, void* d_ws, size_t ws_size,
                              hipStream_t stream)
{
    (void)in_sizes; (void)n_in; (void)ws_size; (void)out_size;

    const int*   toks = (const int*)  d_in[0];
    const float* emb  = (const float*)d_in[1];
    const float* Wx   = (const float*)d_in[2];
    const float* Wh   = (const float*)d_in[3];
    const float* bias = (const float*)d_in[4];
    const float* Wd   = (const float*)d_in[5];
    const float* bd   = (const float*)d_in[6];
    float* out = (float*)d_out;

    // ws layout: hpub [2*BB*UU] u64 (512 KB) | E2 [EE*UU] f32 (512 KB)
    unsigned long long* hpub = (unsigned long long*)d_ws;
    float* E2 = (float*)(hpub + 2 * BB * UU);

    // invalidate tags (0xFFFFFFFF matches no step) -> no stale-tag match on first run
    hipMemsetAsync(hpub, 0xFF, (size_t)(2 * BB * UU) * sizeof(unsigned long long), stream);
    e2_kernel<<<EE, UU, 0, stream>>>(emb, Wx, bias, E2);

    for (int c = 0; c < TT_ / TC; ++c) {
        const int t0 = c * TC;
        rnn_chunk_kernel<<<256, 512, 0, stream>>>(
            toks, E2, Wh, Wd, bd, hpub, out, t0, c == (TT_ / TC - 1));
    }
}